// Round 1
// 297.928 us; speedup vs baseline: 1.4068x; 1.4068x over previous
//
#include <hip/hip_runtime.h>
#include <hip/hip_bf16.h>
#include <stdint.h>

// B=4, C=96, H=W=256, heads=4, d=24, WIN=32, SUB=4
// nW=64 windows(=queries), sNW=64 sub-positions, 1024 keys/problem
// key relabel: key = pr*32 + pw*8 + ww  (attention is key-permutation invariant)
#define PLANE 65536
#define SCALE_F 0.20412414523193154f  // 24^-0.5

typedef __attribute__((ext_vector_type(8))) short short8;
typedef __attribute__((ext_vector_type(4))) float f32x4;

__device__ __forceinline__ unsigned pk2(float a, float b) {
  union { __hip_bfloat162 h; unsigned u; } cv;
  cv.h = __float22bfloat162_rn(make_float2(a, b));
  return cv.u;
}

// ---------------------------------------------------------------------------
// prep: swizzle kv_w into MFMA fragment order (bf16), zero-padded d 24..31.
// (unchanged)
// ---------------------------------------------------------------------------
__global__ __launch_bounds__(256) void prep_kernel(
    const float* __restrict__ kvw, unsigned short* __restrict__ w_a1,
    unsigned short* __restrict__ w_b2) {
  int tid = blockIdx.x * 256 + threadIdx.x;  // 0..3071
  int side = tid / 1536;
  int r = tid % 1536;
  int frag = r >> 6;  // 0..23 = tile*3 + ks
  int lane = r & 63;
  int tile = frag / 3, ks = frag % 3;
  int od = tile * 16 + (lane & 15);
  int c0 = ks * 32 + (lane >> 4) * 8;
  int h = od >> 5, dd = od & 31;
  unsigned out[4] = {0u, 0u, 0u, 0u};
  if (dd < 24) {
    int row = (side == 0) ? (h * 24 + dd) : (96 + h * 24 + dd);
    const float* src = kvw + row * 96 + c0;
    float4 f0 = *(const float4*)src;
    float4 f1 = *(const float4*)(src + 4);
    out[0] = pk2(f0.x, f0.y); out[1] = pk2(f0.z, f0.w);
    out[2] = pk2(f1.x, f1.y); out[3] = pk2(f1.z, f1.w);
  }
  unsigned* dst =
      (unsigned*)((side == 0) ? w_a1 : w_b2) + (frag * 64 + lane) * 4;
  dst[0] = out[0]; dst[1] = out[1]; dst[2] = out[2]; dst[3] = out[3];
}

// ---------------------------------------------------------------------------
// tp v2: transpose x -> xT[b][row][colkey][chgrp] bf16 + fused 4x4 mean-pool.
// Grid 512 = (b, wh, swr, col-half); 512 threads; 24 KB LDS; 2 blocks/CU.
// LDS word = channel PAIR at one column (pk2(ch_even, ch_odd)):
//   - write: 4 x ds_write_b32 at XOR-swizzled cols (verified 2-way banking)
//   - read: output uint4 = 4 direct b32 reads down rows cg*4..cg*4+3
// Swizzle: phys_col = coll ^ ( (coll>>5) | ((cg&7)<<2) ), cg = cpair>>2.
// Same xT / pooled layouts as v1 -> attn & qgemm consumers unchanged.
// ---------------------------------------------------------------------------
__global__ __launch_bounds__(512) void tp_kernel(const float* __restrict__ x,
                                                 unsigned short* __restrict__ xT,
                                                 float* __restrict__ pooled) {
  __shared__ unsigned Lq[48 * 128];  // 24 KB: [cpair 0..47][swizzled col 0..127]
  int blk = blockIdx.x;
  int h = blk & 1;               // column half (cols [h*128, h*128+128))
  int swr = (blk >> 1) & 7;      // sub-row quad within window row
  int wh = (blk >> 4) & 7;       // window row
  int b = blk >> 7;
  int t = threadIdx.x;
  int c4l = t & 31;              // local float4-column 0..31
  int cpg = t >> 5;              // 0..15 channel-pair subgroup
  int ka = c4l >> 3;             // low 2 swizzle bits (== coll>>5)

  float pacc[3][2];
  #pragma unroll
  for (int j = 0; j < 3; ++j) { pacc[j][0] = 0.f; pacc[j][1] = 0.f; }

  for (int pr = 0; pr < 4; ++pr) {
    int r = wh * 32 + swr * 4 + pr;
    const float* xrow =
        x + ((size_t)(b * 96) * 256 + r) * 256 + (h * 32 + c4l) * 4;
    #pragma unroll
    for (int j = 0; j < 3; ++j) {
      int cpair = j * 16 + cpg;        // 0..47
      int cg = cpair >> 2;             // 0..11 (wave-uniform per j)
      const float* pA = xrow + (size_t)(2 * cpair) * PLANE;
      float4 vA = *(const float4*)pA;
      float4 vB = *(const float4*)(pA + PLANE);
      pacc[j][0] += (vA.x + vA.y) + (vA.z + vA.w);
      pacc[j][1] += (vB.x + vB.y) + (vB.z + vB.w);
      unsigned w0 = pk2(vA.x, vB.x), w1 = pk2(vA.y, vB.y);
      unsigned w2 = pk2(vA.z, vB.z), w3 = pk2(vA.w, vB.w);
      int K = ka | ((cg & 7) << 2);
      int base = cpair * 128;
      int c0 = 4 * c4l;
      Lq[base + ((c0 + 0) ^ K)] = w0;
      Lq[base + ((c0 + 1) ^ K)] = w1;
      Lq[base + ((c0 + 2) ^ K)] = w2;
      Lq[base + ((c0 + 3) ^ K)] = w3;
    }
    __syncthreads();
    uint4* dst = (uint4*)xT + (size_t)(b * 256 + r) * 3072;
    #pragma unroll
    for (int it = 0; it < 3; ++it) {
      int id = it * 512 + t;           // 0..1535
      int ckl = id / 12;               // 0..127
      int cg = id - ckl * 12;          // chgrp 0..11
      int sw = ckl >> 4, pw = (ckl >> 2) & 3, wwl = ckl & 3;
      int coll = wwl * 32 + sw * 4 + pw;       // local col 0..127
      int K = wwl | ((cg & 7) << 2);
      int cx = coll ^ K;
      unsigned q0 = Lq[(cg * 4 + 0) * 128 + cx];
      unsigned q1 = Lq[(cg * 4 + 1) * 128 + cx];
      unsigned q2 = Lq[(cg * 4 + 2) * 128 + cx];
      unsigned q3 = Lq[(cg * 4 + 3) * 128 + cx];
      int colkey = sw * 32 + pw * 8 + h * 4 + wwl;
      dst[colkey * 12 + cg] = make_uint4(q0, q1, q2, q3);
    }
    __syncthreads();
  }
  int sw = c4l & 7, ww = h * 4 + (c4l >> 3);
  #pragma unroll
  for (int j = 0; j < 3; ++j)
    #pragma unroll
    for (int e = 0; e < 2; ++e) {
      int ch = 2 * (j * 16 + cpg) + e;
      pooled[(((size_t)(b * 64 + swr * 8 + sw)) * 96 + ch) * 64 + wh * 8 + ww] =
          pacc[j][e] * 0.0625f;
    }
}

// ---------------------------------------------------------------------------
// K1 v2: q_ws[b][s][w][co] = (pooled . q_w^T + q_b) * SCALE   (fp32)
// Grid 1024 = (bs, co-group of 24). c-outer loop: 96 LDS reads/thread (was
// 2304); weights stream via wave-uniform s_loads.
// ---------------------------------------------------------------------------
__global__ __launch_bounds__(256) void qgemm_kernel(
    const float* __restrict__ pooled, const float* __restrict__ qw,
    const float* __restrict__ qb, float* __restrict__ q_ws) {
  __shared__ float pl[64 * 97];
  int blk = blockIdx.x;
  int cog = blk & 3, bs = blk >> 2;
  int t = threadIdx.x;
  const float* src = pooled + (size_t)bs * 6144;
  #pragma unroll
  for (int k = 0; k < 24; ++k) {
    int idx = t + k * 256;  // [c][w]
    int c = idx >> 6, w = idx & 63;
    pl[w * 97 + c] = src[idx];
  }
  __syncthreads();
  int wv = t >> 6, lane = t & 63;
  float acc[6] = {0.f, 0.f, 0.f, 0.f, 0.f, 0.f};
  const float* qwr = qw + (cog * 24 + wv) * 96;  // co = cog*24 + k*4 + wv
  #pragma unroll 4
  for (int c = 0; c < 96; ++c) {
    float v = pl[lane * 97 + c];
    #pragma unroll
    for (int k = 0; k < 6; ++k) acc[k] += v * qwr[k * 384 + c];
  }
  #pragma unroll
  for (int k = 0; k < 6; ++k) {
    int co = cog * 24 + k * 4 + wv;
    q_ws[((size_t)bs * 64 + lane) * 96 + co] = (acc[k] + qb[co]) * SCALE_F;
  }
}

// ---------------------------------------------------------------------------
// K2: fused MFMA KV-projection + attention. (unchanged)
// ---------------------------------------------------------------------------
__global__ __launch_bounds__(512, 2) void attn_kernel(
    const unsigned short* __restrict__ xT,
    const unsigned short* __restrict__ w_a1,
    const unsigned short* __restrict__ w_b2, const float* __restrict__ kvb,
    const float* __restrict__ q_ws, float* __restrict__ o_ws) {
  extern __shared__ __align__(16) char sm[];
  char* Xs = sm;                 // 32768
  char* Ks = sm + 32768;         // 26624 (rows 208)
  char* Vs = sm + 59392;         // 34816 (rows 272)
  char* Ps = sm + 94208;         // 69632 (per-head 17408, rows 272)
  float* lbuf = (float*)sm;      // aliases Xs

  int bs = blockIdx.x;
  int b = bs >> 6, s = bs & 63;
  int sh = s >> 3, sw = s & 7;
  int t = threadIdx.x;
  int w = t >> 6, lane = t & 63;
  int l15 = lane & 15, quad = lane >> 4;

  int mhA1 = w >> 2, nhA1 = w & 3;
  int mhA2 = w & 3, nhA2 = w >> 2;
  int head = w & 3, khalf = w >> 2;
  int nh = w >> 2;

  short8 wa[4][3], wb[4][3];
  #pragma unroll
  for (int i = 0; i < 4; ++i)
    #pragma unroll
    for (int k = 0; k < 3; ++k) {
      wa[i][k] = *(const short8*)(w_a1 + (((4 * mhA1 + i) * 3 + k) * 64 + lane) * 8);
      wb[i][k] = *(const short8*)(w_b2 + (((4 * nhA2 + i) * 3 + k) * 64 + lane) * 8);
    }

  short8 qf[4];
  #pragma unroll
  for (int nt = 0; nt < 4; ++nt) {
    short8 f = {0, 0, 0, 0, 0, 0, 0, 0};
    if (quad < 3) {
      const float* qp =
          q_ws + ((size_t)bs * 64 + nt * 16 + l15) * 96 + head * 24 + quad * 8;
      float4 a = *(const float4*)qp;
      float4 c = *(const float4*)(qp + 4);
      union { short8 s8; unsigned u[4]; } cv;
      cv.u[0] = pk2(a.x, a.y); cv.u[1] = pk2(a.z, a.w);
      cv.u[2] = pk2(c.x, c.y); cv.u[3] = pk2(c.z, c.w);
      f = cv.s8;
    }
    qf[nt] = f;
  }

  float bK[4][4];
  #pragma unroll
  for (int i = 0; i < 4; ++i) {
    int od0 = (4 * mhA1 + i) * 16 + quad * 4;
    #pragma unroll
    for (int r = 0; r < 4; ++r) {
      int od = od0 + r, dd = od & 31, h = od >> 5;
      bK[i][r] = (dd < 24) ? kvb[h * 24 + dd] : 0.f;
    }
  }
  float bV[4];
  #pragma unroll
  for (int i = 0; i < 4; ++i) {
    int vd = (4 * nhA2 + i) * 16 + l15, dd = vd & 31, h = vd >> 5;
    bV[i] = (dd < 24) ? kvb[96 + h * 24 + dd] : 0.f;
  }

  f32x4 zz = {0.f, 0.f, 0.f, 0.f};
  f32x4 oacc[2][2];
  #pragma unroll
  for (int m = 0; m < 2; ++m)
    #pragma unroll
    for (int n = 0; n < 2; ++n) oacc[m][n] = zz;
  float lacc[4] = {0.f, 0.f, 0.f, 0.f};

  const char* sb0 = (const char*)xT + (((size_t)(b * 256 + sh * 4) * 8 + sw) * 6144);

  for (int ti = 0; ti < 8; ++ti) {
    const char* sb = sb0 + (size_t)ti * 32 * 8 * 6144;
    #pragma unroll
    for (int i = 0; i < 3; ++i) {
      int l = i * 512 + t;
      int pr = l / 384;  // wave-uniform
      int rem = l - pr * 384;
      int key = pr * 32 + rem / 12;
      int c = rem - (rem / 12) * 12;
      uint4 v = *(const uint4*)(sb + (size_t)pr * 49152 + (size_t)rem * 16);
      *(uint4*)(Xs + key * 256 + ((c ^ (key & 7)) << 4)) = v;
    }
    __syncthreads();  // B1

    // ---- A1: K-side transposed GEMM ----
    {
      f32x4 acc[4][2];
      #pragma unroll
      for (int i = 0; i < 4; ++i)
        #pragma unroll
        for (int n = 0; n < 2; ++n) {
          f32x4 a; a.x = bK[i][0]; a.y = bK[i][1]; a.z = bK[i][2]; a.w = bK[i][3];
          acc[i][n] = a;
        }
      short8 bx[2][3];
      #pragma unroll
      for (int n = 0; n < 2; ++n) {
        int key = (2 * nhA1 + n) * 16 + l15;
        #pragma unroll
        for (int k = 0; k < 3; ++k)
          bx[n][k] = *(const short8*)(Xs + key * 256 +
                                      (((k * 4 + quad) ^ (key & 7)) << 4));
      }
      #pragma unroll
      for (int i = 0; i < 4; ++i)
        #pragma unroll
        for (int n = 0; n < 2; ++n)
          #pragma unroll
          for (int k = 0; k < 3; ++k)
            acc[i][n] = __builtin_amdgcn_mfma_f32_16x16x32_bf16(
                wa[i][k], bx[n][k], acc[i][n], 0, 0, 0);
      #pragma unroll
      for (int i = 0; i < 4; ++i) {
        int od0 = (4 * mhA1 + i) * 16 + quad * 4;
        int dd0 = od0 & 31;
        if (dd0 < 24) {
          int h = od0 >> 5;
          #pragma unroll
          for (int n = 0; n < 2; ++n) {
            int key = (2 * nhA1 + n) * 16 + l15;
            *(int2*)(Ks + key * 208 + (h * 24 + dd0) * 2) =
                make_int2(pk2(acc[i][n].x, acc[i][n].y),
                          pk2(acc[i][n].z, acc[i][n].w));
          }
        }
      }
    }

    // ---- A2: V-side normal GEMM ----
    {
      short8 ax[2][3];
      #pragma unroll
      for (int m = 0; m < 2; ++m) {
        int key = (2 * mhA2 + m) * 16 + l15;
        #pragma unroll
        for (int k = 0; k < 3; ++k)
          ax[m][k] = *(const short8*)(Xs + key * 256 +
                                      (((k * 4 + quad) ^ (key & 7)) << 4));
      }
      #pragma unroll
      for (int m = 0; m < 2; ++m)
        #pragma unroll
        for (int n = 0; n < 4; ++n) {
          f32x4 acc; acc.x = bV[n]; acc.y = bV[n]; acc.z = bV[n]; acc.w = bV[n];
          #pragma unroll
          for (int k = 0; k < 3; ++k)
            acc = __builtin_amdgcn_mfma_f32_16x16x32_bf16(ax[m][k], wb[n][k],
                                                          acc, 0, 0, 0);
          int vd = (4 * nhA2 + n) * 16 + l15;
          int key0 = (2 * mhA2 + m) * 16 + quad * 4;
          *(int2*)(Vs + vd * 272 + key0 * 2) =
              make_int2(pk2(acc.x, acc.y), pk2(acc.z, acc.w));
        }
    }
    __syncthreads();  // B2

    // ---- S^T = K . Q^T, exp, write P ----
    {
      f32x4 sa[4][4];
      #pragma unroll
      for (int mt = 0; mt < 4; ++mt)
        #pragma unroll
        for (int nt = 0; nt < 4; ++nt) sa[mt][nt] = zz;
      #pragma unroll
      for (int mt = 0; mt < 4; ++mt) {
        int key = khalf * 64 + mt * 16 + l15;
        short8 ak = {0, 0, 0, 0, 0, 0, 0, 0};
        if (quad < 3)
          ak = *(const short8*)(Ks + key * 208 + head * 48 + quad * 16);
        #pragma unroll
        for (int nt = 0; nt < 4; ++nt)
          sa[mt][nt] = __builtin_amdgcn_mfma_f32_16x16x32_bf16(ak, qf[nt],
                                                               sa[mt][nt], 0, 0, 0);
      }
      #pragma unroll
      for (int mt = 0; mt < 4; ++mt) {
        int key0 = khalf * 64 + mt * 16 + quad * 4;
        #pragma unroll
        for (int nt = 0; nt < 4; ++nt) {
          float e0 = __expf(sa[mt][nt].x), e1 = __expf(sa[mt][nt].y);
          float e2 = __expf(sa[mt][nt].z), e3 = __expf(sa[mt][nt].w);
          lacc[nt] += (e0 + e1) + (e2 + e3);
          *(int2*)(Ps + head * 17408 + (nt * 16 + l15) * 272 + key0 * 2) =
              make_int2(pk2(e0, e1), pk2(e2, e3));
        }
      }
      if (ti == 7) {
        #pragma unroll
        for (int nt = 0; nt < 4; ++nt) {
          float v = lacc[nt];
          v += __shfl_xor(v, 16);
          v += __shfl_xor(v, 32);
          if (quad == 0) lbuf[(head * 2 + khalf) * 64 + nt * 16 + l15] = v;
        }
      }
    }
    __syncthreads();  // B3

    // ---- O^T += VT . P ----
    #pragma unroll
    for (int ks = 0; ks < 4; ++ks) {
      short8 av[2];
      #pragma unroll
      for (int mt = 0; mt < 2; ++mt)
        av[mt] = *(const short8*)(Vs + (head * 32 + mt * 16 + l15) * 272 +
                                  ks * 64 + quad * 16);
      #pragma unroll
      for (int n = 0; n < 2; ++n) {
        short8 bp = *(const short8*)(Ps + head * 17408 +
                                     ((2 * nh + n) * 16 + l15) * 272 +
                                     ks * 64 + quad * 16);
        #pragma unroll
        for (int mt = 0; mt < 2; ++mt)
          oacc[mt][n] = __builtin_amdgcn_mfma_f32_16x16x32_bf16(av[mt], bp,
                                                                oacc[mt][n], 0, 0, 0);
      }
    }
  }

  // ---- epilogue ----
  #pragma unroll
  for (int n = 0; n < 2; ++n) {
    int q = (2 * nh + n) * 16 + l15;
    float l = lbuf[(head * 2 + 0) * 64 + q] + lbuf[(head * 2 + 1) * 64 + q];
    float inv = 1.0f / l;
    #pragma unroll
    for (int mt = 0; mt < 2; ++mt)
      #pragma unroll
      for (int r = 0; r < 4; ++r) {
        int d = mt * 16 + quad * 4 + r;
        if (d < 24)
          o_ws[((size_t)bs * 64 + q) * 96 + head * 24 + d] = oacc[mt][n][r] * inv;
      }
  }
}

// ---------------------------------------------------------------------------
// K3 v2: proj + scatter, fused GEMM->scatter, write-coalesced.
// Grid 1024 = (b, wh, sh, co-group of 24); 4 blocks/CU overlap GEMM & stores.
// Lane owns pair = (lane&7)*8 + (lane>>3) so the accumulator is already in
// scatter order (lane = col/4); c-outer loop: 96 LDS reads/thread (was 2304).
// ---------------------------------------------------------------------------
__global__ __launch_bounds__(256) void proj_kernel(const float* __restrict__ o_ws,
                                                   const float* __restrict__ pw,
                                                   const float* __restrict__ pb,
                                                   float* __restrict__ out) {
  __shared__ float ol[64 * 97];
  int blk = blockIdx.x;
  int cog = blk & 3, sh = (blk >> 2) & 7, wh = (blk >> 5) & 7, b = blk >> 8;
  int t = threadIdx.x;

  // stage o tile: pair = sw*8+ww -> 96 contiguous floats each
  #pragma unroll
  for (int k = 0; k < 24; ++k) {
    int id = k * 256 + t;
    int pair = id / 96, c = id - pair * 96;
    int sw = pair >> 3, ww = pair & 7;
    ol[pair * 97 + c] =
        o_ws[(((size_t)(b * 64 + sh * 8 + sw)) * 64 + wh * 8 + ww) * 96 + c];
  }
  __syncthreads();

  int wv = t >> 6, lane = t & 63;
  int pair = (lane & 7) * 8 + (lane >> 3);  // = sw*8+ww for this lane's col
  float acc[6] = {0.f, 0.f, 0.f, 0.f, 0.f, 0.f};
  const float* pwr = pw + (cog * 24 + wv) * 96;  // co = cog*24 + k*4 + wv
  #pragma unroll 4
  for (int c = 0; c < 96; ++c) {
    float v = ol[pair * 97 + c];
    #pragma unroll
    for (int k = 0; k < 6; ++k) acc[k] += v * pwr[k * 384 + c];
  }

  // scatter: wave writes full 1KB rows; lane = col/4; 4 identical ph rows
  #pragma unroll
  for (int k = 0; k < 6; ++k) {
    int co = cog * 24 + k * 4 + wv;
    float val = acc[k] + pb[co];
    float4 pk = make_float4(val, val, val, val);
    size_t rowbase = ((size_t)(b * 96 + co) * 256 + wh * 32 + sh * 4) * 256;
    #pragma unroll
    for (int ph = 0; ph < 4; ++ph)
      *(float4*)(out + rowbase + ph * 256 + lane * 4) = pk;
  }
}

extern "C" void kernel_launch(void* const* d_in, const int* in_sizes, int n_in,
                              void* d_out, int out_size, void* d_ws,
                              size_t ws_size, hipStream_t stream) {
  const float* x = (const float*)d_in[0];
  const float* qw = (const float*)d_in[1];
  const float* qb = (const float*)d_in[2];
  const float* kvw = (const float*)d_in[3];
  const float* kvb = (const float*)d_in[4];
  const float* pw = (const float*)d_in[5];
  const float* pb = (const float*)d_in[6];

  float* pooled = (float*)d_ws;                              // 6 MB
  float* q_ws = pooled + 1572864;                            // 6 MB
  float* o_ws = q_ws + 1572864;                              // 6 MB
  unsigned short* w_a1 = (unsigned short*)(o_ws + 1572864);  // 24 KB
  unsigned short* w_b2 = w_a1 + 12288;                       // 24 KB
  unsigned short* xT = w_b2 + 12288;                         // 50.3 MB

  static int attn_lds = 163840;
  (void)hipFuncSetAttribute((const void*)attn_kernel,
                            hipFuncAttributeMaxDynamicSharedMemorySize,
                            attn_lds);

  hipLaunchKernelGGL(prep_kernel, dim3(12), dim3(256), 0, stream, kvw, w_a1, w_b2);
  hipLaunchKernelGGL(tp_kernel, dim3(512), dim3(512), 0, stream, x, xT, pooled);
  hipLaunchKernelGGL(qgemm_kernel, dim3(1024), dim3(256), 0, stream, pooled, qw,
                     qb, q_ws);
  hipLaunchKernelGGL(attn_kernel, dim3(256), dim3(512), attn_lds, stream, xT,
                     w_a1, w_b2, kvb, q_ws, o_ws);
  hipLaunchKernelGGL(proj_kernel, dim3(1024), dim3(256), 0, stream, o_ws, pw, pb,
                     (float*)d_out);
}